// Round 5
// baseline (257.780 us; speedup 1.0000x reference)
//
#include <hip/hip_runtime.h>
#include <math.h>

#define NSAMP 100
#define F4_PER_ROW 25
#define ROWS_PER_BLOCK 256
#define F4_PER_BLOCK (ROWS_PER_BLOCK * F4_PER_ROW)   // 6400
#define FIXED_SCALE 1073741824.0f                    // 2^30, exact scale

typedef float vfloat4 __attribute__((ext_vector_type(4)));

__device__ __forceinline__ float fast_sigmoid(float x) {
    float e = __builtin_amdgcn_exp2f(-1.44269504088896f * x);
    return __builtin_amdgcn_rcpf(1.0f + e);
}

__device__ __forceinline__ float wave_reduce_sum(float v) {
    #pragma unroll
    for (int off = 32; off > 0; off >>= 1)
        v += __shfl_down(v, off, 64);
    return v;
}

// d_ws layout: [0..7] u64 fixed-point accumulator, [8..11] u32 block counter.
// Both zeroed by a 16B hipMemsetAsync at the top of every kernel_launch call,
// so each graph replay starts clean (d_ws is poisoned once, never re-poisoned).
__global__ __launch_bounds__(256) void stoch_loss_fused(
    const float* __restrict__ logits,
    const float* __restrict__ stddevs,
    const float* __restrict__ targets,
    const float* __restrict__ noise,
    unsigned long long* __restrict__ ws_acc,   // d_ws + 0
    unsigned int* __restrict__ ws_cnt,         // d_ws + 8
    float* __restrict__ out,
    int n)
{
    __shared__ float s_lg[ROWS_PER_BLOCK];
    __shared__ float s_sd[ROWS_PER_BLOCK];
    __shared__ float s_part[F4_PER_BLOCK];
    __shared__ float s_red[4];

    const int tid = threadIdx.x;
    const int r0  = blockIdx.x * ROWS_PER_BLOCK;
    const int r   = r0 + tid;
    const bool valid_row = (r < n);

    s_lg[tid] = valid_row ? logits[r]  : 0.0f;
    s_sd[tid] = valid_row ? stddevs[r] : 0.0f;
    const float tg = valid_row ? targets[r] : 0.0f;   // load early, use late
    __syncthreads();

    const vfloat4* nz = reinterpret_cast<const vfloat4*>(noise);
    const size_t base = (size_t)blockIdx.x * F4_PER_BLOCK;

    if (r0 + ROWS_PER_BLOCK <= n) {
        // Interior block: no bounds checks; nontemporal (noise is 400 MB
        // single-use > L3 -- don't pollute caches).
        #pragma unroll
        for (int i = 0; i < F4_PER_ROW; ++i) {
            const int f_local = i * 256 + tid;
            const int rl = f_local / F4_PER_ROW;
            const vfloat4 v = __builtin_nontemporal_load(&nz[base + f_local]);
            const float lg = s_lg[rl];
            const float sd = s_sd[rl];
            float acc;
            acc  = fast_sigmoid(fmaf(sd, v.x, lg));
            acc += fast_sigmoid(fmaf(sd, v.y, lg));
            acc += fast_sigmoid(fmaf(sd, v.z, lg));
            acc += fast_sigmoid(fmaf(sd, v.w, lg));
            s_part[f_local] = acc;
        }
    } else {
        const size_t f4_limit = (size_t)n * F4_PER_ROW;
        #pragma unroll
        for (int i = 0; i < F4_PER_ROW; ++i) {
            const int f_local = i * 256 + tid;
            const int rl = f_local / F4_PER_ROW;
            const size_t f = base + f_local;
            float acc = 0.0f;
            if (f < f4_limit) {
                const vfloat4 v = __builtin_nontemporal_load(&nz[f]);
                const float lg = s_lg[rl];
                const float sd = s_sd[rl];
                acc  = fast_sigmoid(fmaf(sd, v.x, lg));
                acc += fast_sigmoid(fmaf(sd, v.y, lg));
                acc += fast_sigmoid(fmaf(sd, v.z, lg));
                acc += fast_sigmoid(fmaf(sd, v.w, lg));
            }
            s_part[f_local] = acc;
        }
    }
    __syncthreads();

    float loss = 0.0f;
    if (valid_row) {
        float acc = 0.0f;
        #pragma unroll
        for (int j = 0; j < F4_PER_ROW; ++j)
            acc += s_part[tid * F4_PER_ROW + j];
        const float p = acc * (1.0f / NSAMP);
        const float log_p   = fmaxf(__logf(p), -100.0f);
        const float log_1mp = fmaxf(log1pf(-p), -100.0f);
        loss = -(tg * log_p + (1.0f - tg) * log_1mp);
    }

    float wsum = wave_reduce_sum(loss);
    const int wid  = tid >> 6;
    const int lane = tid & 63;
    if (lane == 0) s_red[wid] = wsum;
    __syncthreads();

    if (tid == 0) {
        const float bsum = (s_red[0] + s_red[1]) + (s_red[2] + s_red[3]);
        // loss >= 0 and bsum <= 256*100; *2^30 is an exact power-of-2 scale
        // -> integer-valued float -> exact u64. Integer atomics are
        // order-invariant => bitwise-deterministic total across replays.
        const unsigned long long q = (unsigned long long)(bsum * FIXED_SCALE);
        atomicAdd(ws_acc, q);
        __threadfence();
        const unsigned int old = atomicAdd(ws_cnt, 1u);
        if (old == gridDim.x - 1) {   // I'm the last block to finish
            __threadfence();
            const unsigned long long tot = atomicAdd(ws_acc, 0ULL);
            out[0] = (float)((double)tot * (1.0 / 1073741824.0) / (double)n);
        }
    }
}

extern "C" void kernel_launch(void* const* d_in, const int* in_sizes, int n_in,
                              void* d_out, int out_size, void* d_ws, size_t ws_size,
                              hipStream_t stream) {
    const float* logits  = (const float*)d_in[0];
    const float* stddevs = (const float*)d_in[1];
    const float* targets = (const float*)d_in[2];
    const float* noise   = (const float*)d_in[3];
    float* out = (float*)d_out;

    const int n = in_sizes[0];
    const int nblocks = (n + ROWS_PER_BLOCK - 1) / ROWS_PER_BLOCK;

    unsigned long long* ws_acc = (unsigned long long*)d_ws;
    unsigned int*       ws_cnt = (unsigned int*)((char*)d_ws + 8);

    // Zero accumulator + counter each call (graph-capturable async memset).
    hipMemsetAsync(d_ws, 0, 16, stream);

    stoch_loss_fused<<<nblocks, 256, 0, stream>>>(logits, stddevs, targets, noise,
                                                  ws_acc, ws_cnt, out, n);
}

// Round 6
// 67.095 us; speedup vs baseline: 3.8420x; 3.8420x over previous
//
#include <hip/hip_runtime.h>
#include <math.h>

#define NSAMP 100
#define F4_PER_ROW 25
#define ROWS_PER_BLOCK 256
#define BLOCK_THREADS 512
#define F4_PER_BLOCK (ROWS_PER_BLOCK * F4_PER_ROW)   // 6400
#define STREAM_ITERS ((F4_PER_BLOCK + BLOCK_THREADS - 1) / BLOCK_THREADS)  // 13

typedef float vfloat4 __attribute__((ext_vector_type(4)));

__device__ __forceinline__ float fast_sigmoid(float x) {
    float e = __builtin_amdgcn_exp2f(-1.44269504088896f * x);
    return __builtin_amdgcn_rcpf(1.0f + e);
}

__device__ __forceinline__ float wave_reduce_sum(float v) {
    #pragma unroll
    for (int off = 32; off > 0; off >>= 1)
        v += __shfl_down(v, off, 64);
    return v;
}

__global__ __launch_bounds__(BLOCK_THREADS) void stoch_loss_rows(
    const float* __restrict__ logits,
    const float* __restrict__ stddevs,
    const float* __restrict__ targets,
    const float* __restrict__ noise,
    float* __restrict__ partial,
    int n)
{
    __shared__ float s_lg[ROWS_PER_BLOCK];
    __shared__ float s_sd[ROWS_PER_BLOCK];
    __shared__ float s_part[F4_PER_BLOCK];
    __shared__ float s_red[BLOCK_THREADS / 64];

    const int tid = threadIdx.x;
    const int r0  = blockIdx.x * ROWS_PER_BLOCK;
    const int r   = r0 + tid;                       // only meaningful for tid<256
    const bool row_owner = (tid < ROWS_PER_BLOCK) && (r < n);

    float tg = 0.0f;
    if (tid < ROWS_PER_BLOCK) {
        s_lg[tid] = row_owner ? logits[r]  : 0.0f;
        s_sd[tid] = row_owner ? stddevs[r] : 0.0f;
        tg        = row_owner ? targets[r] : 0.0f;  // load early, use late
    }
    __syncthreads();

    const vfloat4* nz = reinterpret_cast<const vfloat4*>(noise);
    const size_t base = (size_t)blockIdx.x * F4_PER_BLOCK;

    if (r0 + ROWS_PER_BLOCK <= n) {
        // Interior block: coalesced nontemporal stream over the block's 6400
        // contiguous float4s (noise is 400 MB single-use > L3: don't cache).
        #pragma unroll
        for (int i = 0; i < STREAM_ITERS; ++i) {
            const int f_local = i * BLOCK_THREADS + tid;
            if (i < STREAM_ITERS - 1 || f_local < F4_PER_BLOCK) {
                const int rl = f_local / F4_PER_ROW;
                const vfloat4 v = __builtin_nontemporal_load(&nz[base + f_local]);
                const float lg = s_lg[rl];
                const float sd = s_sd[rl];
                float acc;
                acc  = fast_sigmoid(fmaf(sd, v.x, lg));
                acc += fast_sigmoid(fmaf(sd, v.y, lg));
                acc += fast_sigmoid(fmaf(sd, v.z, lg));
                acc += fast_sigmoid(fmaf(sd, v.w, lg));
                s_part[f_local] = acc;
            }
        }
    } else {
        const size_t f4_limit = (size_t)n * F4_PER_ROW;
        #pragma unroll
        for (int i = 0; i < STREAM_ITERS; ++i) {
            const int f_local = i * BLOCK_THREADS + tid;
            if (f_local < F4_PER_BLOCK) {
                const size_t f = base + f_local;
                float acc = 0.0f;
                if (f < f4_limit) {
                    const int rl = f_local / F4_PER_ROW;
                    const vfloat4 v = __builtin_nontemporal_load(&nz[f]);
                    const float lg = s_lg[rl];
                    const float sd = s_sd[rl];
                    acc  = fast_sigmoid(fmaf(sd, v.x, lg));
                    acc += fast_sigmoid(fmaf(sd, v.y, lg));
                    acc += fast_sigmoid(fmaf(sd, v.z, lg));
                    acc += fast_sigmoid(fmaf(sd, v.w, lg));
                }
                s_part[f_local] = acc;
            }
        }
    }
    __syncthreads();

    // Row-reduce + BCE: threads 0..255 own one row each (stride-25 LDS read
    // = 2-way bank alias = free).
    float loss = 0.0f;
    if (row_owner) {
        float acc = 0.0f;
        #pragma unroll
        for (int j = 0; j < F4_PER_ROW; ++j)
            acc += s_part[tid * F4_PER_ROW + j];
        const float p = acc * (1.0f / NSAMP);
        const float log_p   = fmaxf(__logf(p), -100.0f);
        const float log_1mp = fmaxf(log1pf(-p), -100.0f);
        loss = -(tg * log_p + (1.0f - tg) * log_1mp);
    }

    float wsum = wave_reduce_sum(loss);
    const int wid  = tid >> 6;
    const int lane = tid & 63;
    if (lane == 0) s_red[wid] = wsum;
    __syncthreads();
    if (tid == 0) {
        float b = 0.0f;
        #pragma unroll
        for (int w = 0; w < BLOCK_THREADS / 64; ++w) b += s_red[w];
        partial[blockIdx.x] = b;
    }
}

__global__ __launch_bounds__(1024) void reduce_partial(
    const float* __restrict__ partial, float* __restrict__ out,
    int nparts, float scale)
{
    float s = 0.0f;
    for (int i = threadIdx.x; i < nparts; i += 1024)
        s += partial[i];
    float wsum = wave_reduce_sum(s);
    __shared__ float lds[16];
    const int wid  = threadIdx.x >> 6;
    const int lane = threadIdx.x & 63;
    if (lane == 0) lds[wid] = wsum;
    __syncthreads();
    if (threadIdx.x == 0) {
        float t = 0.0f;
        #pragma unroll
        for (int w = 0; w < 16; ++w) t += lds[w];
        out[0] = t * scale;
    }
}

extern "C" void kernel_launch(void* const* d_in, const int* in_sizes, int n_in,
                              void* d_out, int out_size, void* d_ws, size_t ws_size,
                              hipStream_t stream) {
    const float* logits  = (const float*)d_in[0];
    const float* stddevs = (const float*)d_in[1];
    const float* targets = (const float*)d_in[2];
    const float* noise   = (const float*)d_in[3];
    float* out = (float*)d_out;

    const int n = in_sizes[0];
    const int nblocks = (n + ROWS_PER_BLOCK - 1) / ROWS_PER_BLOCK;
    float* partial = (float*)d_ws;

    stoch_loss_rows<<<nblocks, BLOCK_THREADS, 0, stream>>>(
        logits, stddevs, targets, noise, partial, n);
    reduce_partial<<<1, 1024, 0, stream>>>(partial, out, nblocks, 1.0f / (float)n);
}